// Round 1
// baseline (2048.353 us; speedup 1.0000x reference)
//
#include <hip/hip_runtime.h>

namespace {
constexpr int NB = 1024;   // batch
constexpr int NT = 1024;   // time steps
constexpr int NH = 128;    // hidden
// channels C = 6, x row = 13 floats

typedef __bf16 bf16x8 __attribute__((ext_vector_type(8)));
typedef short  s16x8  __attribute__((ext_vector_type(8)));
typedef float  f32x4  __attribute__((ext_vector_type(4)));

union BF8 { s16x8 s; bf16x8 b; };

__device__ __forceinline__ short f2bf(float f) {   // RNE f32 -> bf16 bits
  unsigned u = __float_as_uint(f);
  return (short)((u + 0x7FFFu + ((u >> 16) & 1u)) >> 16);
}

__device__ __forceinline__ float sigm(float x) { return 1.f / (1.f + __expf(-x)); }

} // namespace

#define MFMA16(a, b, c) __builtin_amdgcn_mfma_f32_16x16x32_bf16(a, b, c, 0, 0, 0)

// One block = 16 batch rows, 8 waves. Wave w owns hidden units [16w,16w+16):
// gate tiles {w, 8+w, 16+w} of the 384-wide gi/gh output, w1 tile w, wu1 tile
// (w-4) for waves 4-7, w2 on wave 0, wu2 on wave 1. All weights held as
// B-fragments in registers (loop-invariant). h state f32 in regs (D-frag
// layout); bf16 copies staged in LDS for A-fragments.
__global__ __launch_bounds__(512, 2)
void grud_fused(const float* __restrict__ x,
                const float* __restrict__ x_mean,
                const float* __restrict__ dxw, const float* __restrict__ dxb,
                const float* __restrict__ dhw, const float* __restrict__ dhb,
                const float* __restrict__ w_ih, const float* __restrict__ w_hh,
                const float* __restrict__ b_ih, const float* __restrict__ b_hh,
                const float* __restrict__ w1,  const float* __restrict__ b1,
                const float* __restrict__ w2,  const float* __restrict__ b2,
                const float* __restrict__ wu1, const float* __restrict__ bu1,
                const float* __restrict__ wu2, const float* __restrict__ bu2,
                float* __restrict__ out)
{
  __shared__ __align__(16) float          xw[2][16][14];   // [buf][row][13+pad]
  __shared__ __align__(16) unsigned short gin[16][32];     // gru_in bf16, k>=12 zero
  __shared__ __align__(16) unsigned short hbf[16 * 128];   // decayed h, swizzled
  __shared__ __align__(16) unsigned short hnbf[16 * 128];  // new h, swizzled
  __shared__ __align__(16) unsigned short y1bf[16 * 128];  // relu(h@w1+b1), swizzled
  __shared__ __align__(16) unsigned short u1bf[16 * 64];   // relu(h@wu1+bu1), swizzled

  const int tid  = threadIdx.x;
  const int lane = tid & 63;
  const int wv   = tid >> 6;       // wave 0..7
  const int lr   = lane & 15;      // row (A) / col (B,D) within tile
  const int lg   = lane >> 4;      // k-group / D row-group
  const int b0   = blockIdx.x * 16;

  // zero the k-pad of gin once (cols 12..31 stay zero forever)
  if (tid < 16 * 32) ((unsigned short*)gin)[tid] = 0;

  // ---------------- weight fragments (registers, loop-invariant) -------------
  bf16x8 bhh[3][4], bgi[3], bw1[4], bq1[4], bq2[4];
  #pragma unroll
  for (int g = 0; g < 3; ++g) {
    const int grow = (g * 8 + wv) * 16 + lr;      // gate row in [0,384)
    #pragma unroll
    for (int s = 0; s < 4; ++s) {
      const float* p = w_hh + grow * NH + s * 32 + lg * 8;
      s16x8 t;
      #pragma unroll
      for (int j = 0; j < 8; ++j) t[j] = f2bf(p[j]);
      BF8 u; u.s = t; bhh[g][s] = u.b;
    }
    { s16x8 t;
      #pragma unroll
      for (int j = 0; j < 8; ++j) {
        const int k = lg * 8 + j;
        t[j] = (k < 12) ? f2bf(w_ih[grow * 12 + k]) : (short)0;
      }
      BF8 u; u.s = t; bgi[g] = u.b; }
  }
  #pragma unroll
  for (int s = 0; s < 4; ++s) {
    const float* p = w1 + (wv * 16 + lr) * NH + s * 32 + lg * 8;
    s16x8 t;
    #pragma unroll
    for (int j = 0; j < 8; ++j) t[j] = f2bf(p[j]);
    BF8 u; u.s = t; bw1[s] = u.b;
  }
  #pragma unroll
  for (int s = 0; s < 4; ++s) {   // wu1 tile (used by waves 4-7; harmless elsewhere)
    const float* p = wu1 + ((wv & 3) * 16 + lr) * NH + s * 32 + lg * 8;
    s16x8 t;
    #pragma unroll
    for (int j = 0; j < 8; ++j) t[j] = f2bf(p[j]);
    BF8 u; u.s = t; bq1[s] = u.b;
  }
  if (wv == 1) {                  // wu2: 2 fragments (K=64)
    #pragma unroll
    for (int s = 0; s < 4; ++s) {
      s16x8 t;
      #pragma unroll
      for (int j = 0; j < 8; ++j)
        t[j] = (lr < 6 && s < 2) ? f2bf(wu2[lr * 64 + s * 32 + lg * 8 + j]) : (short)0;
      BF8 u; u.s = t; bq2[s] = u.b;
    }
  } else {                        // w2 pattern (used by wave 0)
    #pragma unroll
    for (int s = 0; s < 4; ++s) {
      s16x8 t;
      #pragma unroll
      for (int j = 0; j < 8; ++j)
        t[j] = (lr < 6) ? f2bf(w2[lr * NH + s * 32 + lg * 8 + j]) : (short)0;
      BF8 u; u.s = t; bq2[s] = u.b;
    }
  }

  // ---------------- per-lane constants ----------------
  const int   uidx  = wv * 16 + lr;          // this lane's hidden unit
  const float dhw_l = dhw[uidx], dhb_l = dhb[uidx];
  const float br_l  = b_ih[uidx] + b_hh[uidx];
  const float bz_l  = b_ih[128 + uidx] + b_hh[128 + uidx];
  const float bin_l = b_ih[256 + uidx];
  const float bhn_l = b_hh[256 + uidx];
  const float b1_l  = b1[uidx];
  const float bu1_l = bu1[(wv & 3) * 16 + lr];
  const float bo_l  = (lr < 6) ? ((wv == 1) ? bu2[lr] : b2[lr]) : 0.f;

  // x_hat lanes: waves 0-1, items idx = m*6+c for 16 rows x 6 channels
  const int  xi     = wv * 64 + lane;
  const bool xlane  = (wv < 2) && (xi < 96);
  const int  xm_row = xi / 6, xm_c = xi - 6 * (xi / 6);
  float dxw_l = 0.f, dxb_l = 0.f, xmean_l = 0.f;
  if (xlane) { dxw_l = dxw[xm_c]; dxb_l = dxb[xm_c]; xmean_l = x_mean[xm_c]; }

  // ---------------- state ----------------
  float h_prev[4] = {0.f, 0.f, 0.f, 0.f};   // wave's 16-unit slice, D-frag layout
  float run_s = 0.f, xlast_s = 0.f;         // per (row,channel) on x_hat lanes

  // stage x[t=0]
  if (tid < 208) {
    const int rrow = tid / 13, cc = tid - 13 * rrow;
    xw[0][rrow][cc] = x[(size_t)(b0 + rrow) * (NT * 13) + cc];
  }
  __syncthreads();

  const int swz = lr & 7;   // row-XOR for swizzled tiles (row = lr on reads)

  #pragma unroll 1
  for (int t = 0; t < NT; ++t) {
    const int pb = t & 1;

    // ---- phase A: gamma_h decay + stage hd; x_hat + stage gru_in ----
    float hd[4];
    #pragma unroll
    for (int r = 0; r < 4; ++r) {
      const int m = lg * 4 + r;
      const float dt1 = xw[pb][m][12];
      const float gh_ = __expf(-fmaxf(dt1 * dhw_l + dhb_l, 0.f));
      hd[r] = gh_ * h_prev[r];
      hbf[m * 128 + ((((uidx >> 3) ^ (m & 7))) << 3) + (lr & 7)] = (unsigned short)f2bf(hd[r]);
    }
    if (xlane) {
      const float xv  = xw[pb][xm_row][xm_c];
      const float mt  = xw[pb][xm_row][6 + xm_c];
      const float dt1 = xw[pb][xm_row][12];
      const bool obs  = mt > 0.5f;
      run_s   = obs ? 0.f : (run_s + dt1);
      const float gx = __expf(-fmaxf(run_s * dxw_l + dxb_l, 0.f));
      xlast_s = obs ? xv : xlast_s;
      const float xh = mt * xv + (1.f - mt) * (gx * xlast_s + (1.f - gx) * xmean_l);
      gin[xm_row][xm_c]     = (unsigned short)f2bf(xh);
      gin[xm_row][6 + xm_c] = (unsigned short)f2bf(mt);
    }
    __syncthreads();   // barrier 1

    // ---- phase C: prefetch x[t+1]; A-frags; gi/gh MFMAs ----
    float xpre = 0.f;
    if (t + 1 < NT && tid < 208) {
      const int rrow = tid / 13, cc = tid - 13 * rrow;
      xpre = x[(size_t)(b0 + rrow) * (NT * 13) + (t + 1) * 13 + cc];
    }
    bf16x8 agru, ah[4];
    { BF8 u; u.s = *(const s16x8*)&gin[lr][lg * 8]; agru = u.b; }
    #pragma unroll
    for (int s = 0; s < 4; ++s) {
      BF8 u; u.s = *(const s16x8*)&hbf[lr * 128 + (((s * 4 + lg) ^ swz) << 3)];
      ah[s] = u.b;
    }
    f32x4 ai[3], ahc[3];
    #pragma unroll
    for (int g = 0; g < 3; ++g) {
      f32x4 z4 = {0.f, 0.f, 0.f, 0.f};
      ai[g] = MFMA16(agru, bgi[g], z4);
      f32x4 acc = {0.f, 0.f, 0.f, 0.f};
      #pragma unroll
      for (int s = 0; s < 4; ++s) acc = MFMA16(ah[s], bhh[g][s], acc);
      ahc[g] = acc;
    }

    // ---- phase D: gates, h update, stage new h ----
    #pragma unroll
    for (int r = 0; r < 4; ++r) {
      const int m = lg * 4 + r;
      const float rr = sigm(ai[0][r] + ahc[0][r] + br_l);
      const float zz = sigm(ai[1][r] + ahc[1][r] + bz_l);
      const float na = ai[2][r] + bin_l + rr * (ahc[2][r] + bhn_l);
      const float nn = 1.f - 2.f / (__expf(2.f * na) + 1.f);
      const float hn = (1.f - zz) * nn + zz * hd[r];
      h_prev[r] = hn;
      hnbf[m * 128 + ((((uidx >> 3) ^ (m & 7))) << 3) + (lr & 7)] = (unsigned short)f2bf(hn);
    }
    __syncthreads();   // barrier 2

    // ---- phase E: head layer 1 (all waves w1; waves 4-7 also wu1) ----
    bf16x8 ahn[4];
    #pragma unroll
    for (int s = 0; s < 4; ++s) {
      BF8 u; u.s = *(const s16x8*)&hnbf[lr * 128 + (((s * 4 + lg) ^ swz) << 3)];
      ahn[s] = u.b;
    }
    {
      f32x4 acc = {0.f, 0.f, 0.f, 0.f};
      #pragma unroll
      for (int s = 0; s < 4; ++s) acc = MFMA16(ahn[s], bw1[s], acc);
      #pragma unroll
      for (int r = 0; r < 4; ++r) {
        const int m = lg * 4 + r;
        const float yv = fmaxf(acc[r] + b1_l, 0.f);
        y1bf[m * 128 + ((((uidx >> 3) ^ (m & 7))) << 3) + (lr & 7)] = (unsigned short)f2bf(yv);
      }
    }
    if (wv >= 4) {
      f32x4 acc = {0.f, 0.f, 0.f, 0.f};
      #pragma unroll
      for (int s = 0; s < 4; ++s) acc = MFMA16(ahn[s], bq1[s], acc);
      const int uu = (wv - 4) * 16 + lr;
      #pragma unroll
      for (int r = 0; r < 4; ++r) {
        const int m = lg * 4 + r;
        const float yv = fmaxf(acc[r] + bu1_l, 0.f);
        u1bf[m * 64 + ((((uu >> 3) ^ (m & 7))) << 3) + (lr & 7)] = (unsigned short)f2bf(yv);
      }
    }
    if (t + 1 < NT && tid < 208) {
      const int rrow = tid / 13, cc = tid - 13 * rrow;
      xw[pb ^ 1][rrow][cc] = xpre;
    }
    __syncthreads();   // barrier 3

    // ---- phase F: head layer 2 + global stores (waves 0 and 1 only) ----
    if (wv == 0) {
      bf16x8 ay[4];
      #pragma unroll
      for (int s = 0; s < 4; ++s) {
        BF8 u; u.s = *(const s16x8*)&y1bf[lr * 128 + (((s * 4 + lg) ^ swz) << 3)];
        ay[s] = u.b;
      }
      f32x4 acc = {0.f, 0.f, 0.f, 0.f};
      #pragma unroll
      for (int s = 0; s < 4; ++s) acc = MFMA16(ay[s], bq2[s], acc);
      if (lr < 6) {
        #pragma unroll
        for (int r = 0; r < 4; ++r) {
          const int m = lg * 4 + r;
          out[((size_t)(b0 + m) * NT + t) * 6 + lr] = acc[r] + bo_l;
        }
      }
    } else if (wv == 1) {
      bf16x8 au[2];
      #pragma unroll
      for (int s = 0; s < 2; ++s) {
        BF8 u; u.s = *(const s16x8*)&u1bf[lr * 64 + (((s * 4 + lg) ^ swz) << 3)];
        au[s] = u.b;
      }
      f32x4 acc = {0.f, 0.f, 0.f, 0.f};
      #pragma unroll
      for (int s = 0; s < 2; ++s) acc = MFMA16(au[s], bq2[s], acc);
      if (lr < 6) {
        #pragma unroll
        for (int r = 0; r < 4; ++r) {
          const int m = lg * 4 + r;
          const float xa = acc[r] + bo_l;
          const float sp = fmaxf(xa, 0.f) + __logf(1.f + __expf(-fabsf(xa)));
          out[(size_t)NB * NT * 6 + ((size_t)(b0 + m) * NT + t) * 6 + lr] = sp;
        }
      }
    }
    // no barrier needed here: next phase-A writes touch buffers whose last
    // reads were before barrier 2/3 of this step.
  }
}

extern "C" void kernel_launch(void* const* d_in, const int* in_sizes, int n_in,
                              void* d_out, int out_size, void* d_ws, size_t ws_size,
                              hipStream_t stream) {
  (void)in_sizes; (void)n_in; (void)out_size; (void)d_ws; (void)ws_size;
  const float* p[18];
  for (int i = 0; i < 18; ++i) p[i] = (const float*)d_in[i];
  hipLaunchKernelGGL(grud_fused, dim3(64), dim3(512), 0, stream,
                     p[0], p[1], p[2], p[3], p[4], p[5], p[6], p[7], p[8], p[9],
                     p[10], p[11], p[12], p[13], p[14], p[15], p[16], p[17],
                     (float*)d_out);
}

// Round 2
// 1330.974 us; speedup vs baseline: 1.5390x; 1.5390x over previous
//
#include <hip/hip_runtime.h>

namespace {
constexpr int NB = 1024, NT = 1024, NH = 128, NC = 6;
constexpr float L2E = 1.4426950408889634f;

typedef __bf16 bf16x8 __attribute__((ext_vector_type(8)));
typedef float  f32x4  __attribute__((ext_vector_type(4)));
typedef int    i32x4  __attribute__((ext_vector_type(4)));
union FRAG { i32x4 i; bf16x8 b; };

__device__ __forceinline__ unsigned short bfb(float f) {
  union { __bf16 h; unsigned short u; } c; c.h = (__bf16)f; return c.u;
}
__device__ __forceinline__ unsigned pkbf(float a, float b) {
  return (unsigned)bfb(a) | ((unsigned)bfb(b) << 16);
}
__device__ __forceinline__ float ex2(float x) { return __builtin_amdgcn_exp2f(x); }
__device__ __forceinline__ float rcpf_(float x) { return __builtin_amdgcn_rcpf(x); }
} // namespace

#define MFMA(a, b, c) __builtin_amdgcn_mfma_f32_16x16x32_bf16(a, b, c, 0, 0, 0)

// ---------------------------------------------------------------------------
// Kernel 1: GRU-D recurrence only. 64 blocks x 8 waves. Wave w owns hidden
// units [16w,16w+16). One barrier per step. Weights (log2e-scaled, biases
// folded into a constant-1 K-column of gru_in) live in registers. x_hat and
// m-fragments pipelined one step ahead. h_t written to ws as bf16.
// ---------------------------------------------------------------------------
__global__ __launch_bounds__(512, 2)
void grud_rnn(const float* __restrict__ x,   const float* __restrict__ x_mean,
              const float* __restrict__ dxw, const float* __restrict__ dxb,
              const float* __restrict__ dhw, const float* __restrict__ dhb,
              const float* __restrict__ w_ih, const float* __restrict__ w_hh,
              const float* __restrict__ b_ih, const float* __restrict__ b_hh,
              unsigned short* __restrict__ hws, float* __restrict__ hstate,
              float* __restrict__ runst, float* __restrict__ xlst,
              int t0, int Tc)
{
  __shared__ __align__(16) float          xw[2][16][14];   // x rows (13+pad)
  __shared__ __align__(16) unsigned short gin[2][16][8];   // x_hat bf16 rows
  __shared__ __align__(16) unsigned short hdb[2][16 * 128];// decayed h, swizzled

  const int tid = threadIdx.x, lane = tid & 63, wv = tid >> 6;
  const int lr = lane & 15, lg = lane >> 4;
  const int b0 = blockIdx.x * 16;
  const int uidx = wv * 16 + lr;

  // ---- weight fragments (scaled: r,z by -log2e; n by +2log2e) ----
  FRAG bhh[3][4], bgi[3];
  #pragma unroll
  for (int g = 0; g < 3; ++g) {
    const float sc = (g < 2) ? -L2E : 2.f * L2E;
    const int grow = g * 128 + uidx;
    #pragma unroll
    for (int s = 0; s < 4; ++s) {
      const float4* p = (const float4*)(w_hh + (size_t)grow * NH + s * 32 + lg * 8);
      float4 a = p[0], b = p[1];
      FRAG f;
      f.i[0] = pkbf(a.x * sc, a.y * sc); f.i[1] = pkbf(a.z * sc, a.w * sc);
      f.i[2] = pkbf(b.x * sc, b.y * sc); f.i[3] = pkbf(b.z * sc, b.w * sc);
      bhh[g][s] = f;
    }
    FRAG f; f.i[0] = f.i[1] = f.i[2] = f.i[3] = 0;
    if (lg == 0) {
      const float* p = w_ih + (size_t)grow * 12;
      f.i[0] = pkbf(p[0] * sc, p[1] * sc); f.i[1] = pkbf(p[2] * sc, p[3] * sc);
      f.i[2] = pkbf(p[4] * sc, p[5] * sc); f.i[3] = pkbf(p[6] * sc, p[7] * sc);
    } else if (lg == 1) {
      const float* p = w_ih + (size_t)grow * 12;
      const float bias = (g < 2) ? (b_ih[grow] + b_hh[grow]) : b_ih[grow];
      f.i[0] = pkbf(p[8] * sc, p[9] * sc); f.i[1] = pkbf(p[10] * sc, p[11] * sc);
      f.i[2] = pkbf(bias * sc, 0.f);       // K=12 bias column (A side holds 1.0)
    }
    bgi[g] = f;
  }
  const float bhnS = b_hh[256 + uidx] * (2.f * L2E);
  const float dhwS = -L2E * dhw[uidx], dhbS = -L2E * dhb[uidx];

  // ---- x_hat lanes: waves 0-3, lanes 0..23 -> item = (row, channel) ----
  const int  item = wv * 24 + lane;
  const bool xl = (wv < 4) && (lane < 24);
  const int  xrow = item / 6, xch = item - 6 * (item / 6);
  float dxwS = 0.f, dxbS = 0.f, xmean_l = 0.f, run = 0.f, xlast = 0.f;
  if (xl) {
    dxwS = -L2E * dxw[xch]; dxbS = -L2E * dxb[xch]; xmean_l = x_mean[xch];
    if (t0 > 0) { run = runst[(b0 + xrow) * 6 + xch]; xlast = xlst[(b0 + xrow) * 6 + xch]; }
  }

  // ---- h state (D-frag layout) ----
  f32x4 hn;
  #pragma unroll
  for (int r = 0; r < 4; ++r) {
    const int m = 4 * lg + r;
    hn[r] = (t0 > 0) ? hstate[(size_t)(b0 + m) * NH + uidx] : 0.f;
  }

  // ---- prologue: stage x[t0], x[t0+1] ----
  int rrow = 0, rcc = 0; float xr0 = 0.f, xr1 = 0.f, xr2 = 0.f;
  const bool sl = tid < 208;
  if (sl) { rrow = tid / 13; rcc = tid - 13 * rrow; }
  const float* xbase = x + (size_t)(b0 + rrow) * (NT * 13) + rcc;
  if (sl) {
    xr0 = xbase[(size_t)t0 * 13];
    xr1 = xbase[(size_t)(t0 + 1 < NT ? t0 + 1 : NT - 1) * 13];
  }
  if (sl) { xw[t0 & 1][rrow][rcc] = xr0; xw[(t0 + 1) & 1][rrow][rcc] = xr1; }
  __syncthreads();

  // hd_{t0}, x_hat_{t0}, m-regs for agru_{t0}
  f32x4 hd;
  #pragma unroll
  for (int r = 0; r < 4; ++r) {
    const int m = 4 * lg + r;
    const float dtv = xw[t0 & 1][m][12];
    const float g2 = ex2(fminf(dtv * dhwS + dhbS, 0.f));
    hd[r] = g2 * hn[r];
    hdb[t0 & 1][m * 128 + (((uidx >> 3) ^ (m & 7)) << 3) + (lr & 7)] = bfb(hd[r]);
  }
  if (xl) {
    const float xv = xw[t0 & 1][xrow][xch], mt = xw[t0 & 1][xrow][6 + xch];
    const float dtv = xw[t0 & 1][xrow][12];
    const bool obs = mt > 0.5f;
    run = obs ? 0.f : run + dtv;
    const float gx = ex2(fminf(run * dxwS + dxbS, 0.f));
    xlast = obs ? xv : xlast;
    const float xh = mt * xv + (1.f - mt) * (gx * xlast + (1.f - gx) * xmean_l);
    gin[t0 & 1][xrow][xch] = bfb(xh);
  }
  unsigned mr0 = 0, mr1 = 0;
  if (lg == 0) {
    mr0 = pkbf(xw[t0 & 1][lr][6], xw[t0 & 1][lr][7]);
  } else if (lg == 1) {
    mr0 = pkbf(xw[t0 & 1][lr][8], xw[t0 & 1][lr][9]);
    mr1 = pkbf(xw[t0 & 1][lr][10], xw[t0 & 1][lr][11]);
  }
  if (sl) xr2 = xbase[(size_t)(t0 + 2 < NT ? t0 + 2 : NT - 1) * 13];
  __syncthreads();

  // ---- main loop: ONE barrier per step ----
  const int tend = t0 + Tc;
  #pragma unroll 1
  for (int t = t0; t < tend; ++t) {
    const int cb = t & 1, nb = cb ^ 1;

    // A-fragment reads (current step)
    FRAG ag;
    {
      i32x4 gv = *(const i32x4*)&gin[cb][lr][0];
      if (lg == 0)      { ag.i[0] = gv[0]; ag.i[1] = gv[1]; ag.i[2] = gv[2]; ag.i[3] = (int)mr0; }
      else if (lg == 1) { ag.i[0] = (int)mr0; ag.i[1] = (int)mr1; ag.i[2] = 0x00003f80; ag.i[3] = 0; }
      else              { ag.i[0] = ag.i[1] = ag.i[2] = ag.i[3] = 0; }
    }
    FRAG ah[4];
    #pragma unroll
    for (int s = 0; s < 4; ++s)
      ah[s].i = *(const i32x4*)&hdb[cb][lr * 128 + (((s * 4 + lg) ^ (lr & 7)) << 3)];

    // dt_{t+1} (valid whole step; used late)
    float dtn[4];
    #pragma unroll
    for (int r = 0; r < 4; ++r) dtn[r] = xw[nb][4 * lg + r][12];

    // stage x[t+2] into freed buffer; issue load of x[t+3]
    if (sl) xw[cb][rrow][rcc] = xr2;
    if (sl) xr2 = xbase[(size_t)(t + 3 < NT ? t + 3 : NT - 1) * 13];

    // MFMAs: gi (K=12+bias) and gh (K=128)
    f32x4 ai[3], ac[3];
    #pragma unroll
    for (int g = 0; g < 3; ++g) {
      f32x4 z4 = {0.f, 0.f, 0.f, 0.f};
      ai[g] = MFMA(ag.b, bgi[g].b, z4);
      f32x4 a2 = {0.f, 0.f, 0.f, 0.f};
      #pragma unroll
      for (int s = 0; s < 4; ++s) a2 = MFMA(ah[s].b, bhh[g][s].b, a2);
      ac[g] = a2;
    }

    // gates (inputs pre-scaled: r,z by -log2e -> sigmoid = rcp(1+exp2);
    // n by +2log2e -> tanh = 1 - 2*rcp(1+exp2))
    f32x4 xr_ = ai[0] + ac[0];
    f32x4 xz_ = ai[1] + ac[1];
    f32x4 hnb = ac[2] + bhnS;
    #pragma unroll
    for (int r = 0; r < 4; ++r) {
      const float rr = rcpf_(1.f + ex2(xr_[r]));
      const float zz = rcpf_(1.f + ex2(xz_[r]));
      const float na = ai[2][r] + rr * hnb[r];
      const float nn = 1.f - 2.f * rcpf_(1.f + ex2(na));
      hn[r] = nn + zz * (hd[r] - nn);
    }

    // stream h_t to ws (bf16)
    #pragma unroll
    for (int r = 0; r < 4; ++r) {
      const int m = 4 * lg + r;
      hws[((size_t)(b0 + m) * Tc + (t - t0)) * 128 + uidx] = bfb(hn[r]);
    }

    // late phase: prepare step t+1 (decay-at-write, x_hat, m-frags)
    if (t + 1 < tend) {
      #pragma unroll
      for (int r = 0; r < 4; ++r) {
        const int m = 4 * lg + r;
        const float g2 = ex2(fminf(dtn[r] * dhwS + dhbS, 0.f));
        hd[r] = g2 * hn[r];
        hdb[nb][m * 128 + (((uidx >> 3) ^ (m & 7)) << 3) + (lr & 7)] = bfb(hd[r]);
      }
      if (xl) {
        const float xv = xw[nb][xrow][xch], mt = xw[nb][xrow][6 + xch];
        const float dtv = xw[nb][xrow][12];
        const bool obs = mt > 0.5f;
        run = obs ? 0.f : run + dtv;
        const float gx = ex2(fminf(run * dxwS + dxbS, 0.f));
        xlast = obs ? xv : xlast;
        const float xh = mt * xv + (1.f - mt) * (gx * xlast + (1.f - gx) * xmean_l);
        gin[nb][xrow][xch] = bfb(xh);
      }
      if (lg == 0) {
        mr0 = pkbf(xw[nb][lr][6], xw[nb][lr][7]);
      } else if (lg == 1) {
        mr0 = pkbf(xw[nb][lr][8], xw[nb][lr][9]);
        mr1 = pkbf(xw[nb][lr][10], xw[nb][lr][11]);
      }
    }
    __syncthreads();
  }

  // ---- carry state to next chunk ----
  #pragma unroll
  for (int r = 0; r < 4; ++r) {
    const int m = 4 * lg + r;
    hstate[(size_t)(b0 + m) * NH + uidx] = hn[r];
  }
  if (xl) { runst[(b0 + xrow) * 6 + xch] = run; xlst[(b0 + xrow) * 6 + xch] = xlast; }
}

// ---------------------------------------------------------------------------
// Kernel 2: heads. Dense batched GEMM over h rows. Block = 256 thr (4 waves),
// 64 rows. Wave w owns w1 col-tiles {2w,2w+1}, wu1 tile w, then finishes
// row-tile w with w2/wu2. Full-chip parallel.
// ---------------------------------------------------------------------------
__global__ __launch_bounds__(256, 2)
void grud_head(const unsigned short* __restrict__ hws,
               const float* __restrict__ w1,  const float* __restrict__ b1,
               const float* __restrict__ w2,  const float* __restrict__ b2,
               const float* __restrict__ wu1, const float* __restrict__ bu1,
               const float* __restrict__ wu2, const float* __restrict__ bu2,
               float* __restrict__ out, int t0, int tcsh)
{
  __shared__ __align__(16) unsigned short hs [64 * 128];
  __shared__ __align__(16) unsigned short y1s[64 * 128];
  __shared__ __align__(16) unsigned short u1s[64 * 64];

  const int tid = threadIdx.x, lane = tid & 63, wv = tid >> 6;
  const int lr = lane & 15, lg = lane >> 4;
  const int row0 = blockIdx.x * 64;

  // stage h (global -> swizzled LDS)
  {
    const int rl = tid >> 2, q = tid & 3;
    const unsigned short* srcp = hws + (size_t)(row0 + rl) * 128 + q * 32;
    #pragma unroll
    for (int i = 0; i < 4; ++i) {
      i32x4 v = *(const i32x4*)(srcp + i * 8);
      *(i32x4*)&hs[rl * 128 + (((q * 4 + i) ^ (rl & 7)) << 3)] = v;
    }
  }

  // weight fragments
  FRAG bw1[2][4], bq1[4], bw2[4], bq2[2];
  const int ct0 = wv * 2, ct1 = wv * 2 + 1;
  #pragma unroll
  for (int s = 0; s < 4; ++s) {
    {
      const float4* p = (const float4*)(w1 + (size_t)(ct0 * 16 + lr) * 128 + s * 32 + lg * 8);
      float4 a = p[0], b = p[1]; FRAG f;
      f.i[0] = pkbf(a.x, a.y); f.i[1] = pkbf(a.z, a.w);
      f.i[2] = pkbf(b.x, b.y); f.i[3] = pkbf(b.z, b.w);
      bw1[0][s] = f;
    }
    {
      const float4* p = (const float4*)(w1 + (size_t)(ct1 * 16 + lr) * 128 + s * 32 + lg * 8);
      float4 a = p[0], b = p[1]; FRAG f;
      f.i[0] = pkbf(a.x, a.y); f.i[1] = pkbf(a.z, a.w);
      f.i[2] = pkbf(b.x, b.y); f.i[3] = pkbf(b.z, b.w);
      bw1[1][s] = f;
    }
    {
      const float4* p = (const float4*)(wu1 + (size_t)(wv * 16 + lr) * 128 + s * 32 + lg * 8);
      float4 a = p[0], b = p[1]; FRAG f;
      f.i[0] = pkbf(a.x, a.y); f.i[1] = pkbf(a.z, a.w);
      f.i[2] = pkbf(b.x, b.y); f.i[3] = pkbf(b.z, b.w);
      bq1[s] = f;
    }
    {
      FRAG f; f.i[0] = f.i[1] = f.i[2] = f.i[3] = 0;
      if (lr < 6) {
        const float4* p = (const float4*)(w2 + (size_t)lr * 128 + s * 32 + lg * 8);
        float4 a = p[0], b = p[1];
        f.i[0] = pkbf(a.x, a.y); f.i[1] = pkbf(a.z, a.w);
        f.i[2] = pkbf(b.x, b.y); f.i[3] = pkbf(b.z, b.w);
      }
      bw2[s] = f;
    }
    if (s < 2) {
      FRAG f; f.i[0] = f.i[1] = f.i[2] = f.i[3] = 0;
      if (lr < 6) {
        const float4* p = (const float4*)(wu2 + (size_t)lr * 64 + s * 32 + lg * 8);
        float4 a = p[0], b = p[1];
        f.i[0] = pkbf(a.x, a.y); f.i[1] = pkbf(a.z, a.w);
        f.i[2] = pkbf(b.x, b.y); f.i[3] = pkbf(b.z, b.w);
      }
      bq2[s] = f;
    }
  }
  const float b1a = b1[ct0 * 16 + lr], b1b = b1[ct1 * 16 + lr], bu1l = bu1[wv * 16 + lr];
  const float b2l = (lr < 6) ? b2[lr] : 0.f, bu2l = (lr < 6) ? bu2[lr] : 0.f;
  __syncthreads();

  // layer 1
  #pragma unroll
  for (int rt = 0; rt < 4; ++rt) {
    FRAG ah[4];
    #pragma unroll
    for (int s = 0; s < 4; ++s)
      ah[s].i = *(const i32x4*)&hs[(rt * 16 + lr) * 128 + (((s * 4 + lg) ^ (lr & 7)) << 3)];
    f32x4 a0 = {0.f,0.f,0.f,0.f}, a1 = {0.f,0.f,0.f,0.f}, au = {0.f,0.f,0.f,0.f};
    #pragma unroll
    for (int s = 0; s < 4; ++s) {
      a0 = MFMA(ah[s].b, bw1[0][s].b, a0);
      a1 = MFMA(ah[s].b, bw1[1][s].b, a1);
      au = MFMA(ah[s].b, bq1[s].b, au);
    }
    #pragma unroll
    for (int r = 0; r < 4; ++r) {
      const int m = rt * 16 + 4 * lg + r;
      const int c0 = ct0 * 16 + lr, c1 = ct1 * 16 + lr, cu = wv * 16 + lr;
      y1s[m * 128 + (((c0 >> 3) ^ (m & 7)) << 3) + (c0 & 7)] = bfb(fmaxf(a0[r] + b1a, 0.f));
      y1s[m * 128 + (((c1 >> 3) ^ (m & 7)) << 3) + (c1 & 7)] = bfb(fmaxf(a1[r] + b1b, 0.f));
      u1s[m * 64  + (((cu >> 3) ^ (m & 7)) << 3) + (cu & 7)] = bfb(fmaxf(au[r] + bu1l, 0.f));
    }
  }
  __syncthreads();

  // layer 2 + stores (wave w finishes row-tile w)
  FRAG ay[4], auf[2];
  #pragma unroll
  for (int s = 0; s < 4; ++s)
    ay[s].i = *(const i32x4*)&y1s[(wv * 16 + lr) * 128 + (((s * 4 + lg) ^ (lr & 7)) << 3)];
  #pragma unroll
  for (int s = 0; s < 2; ++s)
    auf[s].i = *(const i32x4*)&u1s[(wv * 16 + lr) * 64 + (((s * 4 + lg) ^ (lr & 7)) << 3)];
  f32x4 ap = {0.f,0.f,0.f,0.f}, aq = {0.f,0.f,0.f,0.f};
  #pragma unroll
  for (int s = 0; s < 4; ++s) ap = MFMA(ay[s].b, bw2[s].b, ap);
  #pragma unroll
  for (int s = 0; s < 2; ++s) aq = MFMA(auf[s].b, bq2[s].b, aq);

  if (lr < 6) {
    const int Tcm = (1 << tcsh) - 1;
    #pragma unroll
    for (int r = 0; r < 4; ++r) {
      const int R = row0 + wv * 16 + 4 * lg + r;
      const int b = R >> tcsh, ti = R & Tcm;
      const size_t o = ((size_t)b * NT + (t0 + ti)) * 6 + lr;
      out[o] = ap[r] + b2l;
      const float xa = aq[r] + bu2l;
      const float sp = fmaxf(xa, 0.f) +
          0.6931471805599453f * __builtin_amdgcn_logf(1.f + ex2(-fabsf(xa) * L2E));
      out[(size_t)NB * NT * 6 + o] = sp;
    }
  }
}

extern "C" void kernel_launch(void* const* d_in, const int* in_sizes, int n_in,
                              void* d_out, int out_size, void* d_ws, size_t ws_size,
                              hipStream_t stream) {
  (void)in_sizes; (void)n_in; (void)out_size;
  const float* p[18];
  for (int i = 0; i < 18; ++i) p[i] = (const float*)d_in[i];

  // adaptive T-chunking to fit ws: hbuf = 1024*Tc*128*2 B + carried state
  const size_t STATE = (size_t)1024 * 128 * 4 + 2 * (size_t)1024 * 6 * 4;
  int Tc = 1024;
  while (Tc > 16 && (size_t)1024 * Tc * 256 + STATE > ws_size) Tc >>= 1;
  int tcsh = 0; while ((1 << tcsh) < Tc) ++tcsh;

  char* w = (char*)d_ws;
  unsigned short* hbuf = (unsigned short*)w;
  float* hstate = (float*)(w + (size_t)1024 * Tc * 256);
  float* runst  = hstate + 1024 * 128;
  float* xlst   = runst + 1024 * 6;

  for (int t0 = 0; t0 < NT; t0 += Tc) {
    hipLaunchKernelGGL(grud_rnn, dim3(64), dim3(512), 0, stream,
                       p[0], p[1], p[2], p[3], p[4], p[5], p[6], p[7], p[8], p[9],
                       hbuf, hstate, runst, xlst, t0, Tc);
    hipLaunchKernelGGL(grud_head, dim3((1024 * Tc) / 64), dim3(256), 0, stream,
                       hbuf, p[10], p[11], p[12], p[13], p[14], p[15], p[16], p[17],
                       (float*)d_out, t0, tcsh);
  }
}